// Round 3
// baseline (455.294 us; speedup 1.0000x reference)
//
#include <hip/hip_runtime.h>
#include <stdint.h>

static constexpr int CDIM = 32;     // channels
static constexpr int NPIX = 16384;  // H*W = 128*128

__device__ __forceinline__ uint32_t f2bf(float f) {
    // round-to-nearest-even f32 -> bf16 (inputs are finite gaussians; no NaN care)
    uint32_t u = __float_as_uint(f);
    return (u + 0x7fffu + ((u >> 16) & 1u)) >> 16;
}

// ---------------------------------------------------------------------------
// Kernel 1: layout prep.
//   key_feat  [B][C][N] f32  -> key8  [B*N][32] bf16 rows (64B, line-aligned)
//   query_feat[B][C][N] f32  -> qt    [B*N][32] f32 rows (128B)
//   seg32     [B*N] i32      -> seg8  [B*N] u8   (values 0..63)
// Reads coalesced along N per channel; row writes merge in L2.
// ---------------------------------------------------------------------------
__global__ __launch_bounds__(256)
void prep_kernel(const float* __restrict__ key_f,
                 const float* __restrict__ query_f,
                 const int* __restrict__ seg32,
                 uint8_t* __restrict__ key8,
                 float* __restrict__ qt,
                 uint8_t* __restrict__ seg8,
                 int N, int rows)
{
    int g = blockIdx.x * 256 + threadIdx.x;
    if (g >= rows) return;
    int b = g / N, n = g - b * N;
    const size_t cb = (size_t)b * CDIM;

    uint32_t packed[16];
#pragma unroll
    for (int c = 0; c < CDIM; c += 2) {
        float f0 = key_f[(cb + c) * N + n];
        float f1 = key_f[(cb + c + 1) * N + n];
        packed[c >> 1] = f2bf(f0) | (f2bf(f1) << 16);
    }
    uint4* kout = (uint4*)(key8 + ((size_t)g << 6));
#pragma unroll
    for (int j = 0; j < 4; ++j)
        kout[j] = make_uint4(packed[4*j], packed[4*j+1], packed[4*j+2], packed[4*j+3]);

    float4* qout = (float4*)(qt + (size_t)g * CDIM);
#pragma unroll
    for (int c = 0; c < CDIM; c += 4) {
        float4 v;
        v.x = query_f[(cb + c    ) * N + n];
        v.y = query_f[(cb + c + 1) * N + n];
        v.z = query_f[(cb + c + 2) * N + n];
        v.w = query_f[(cb + c + 3) * N + n];
        qout[c >> 2] = v;
    }
    seg8[g] = (uint8_t)seg32[g];
}

// ---------------------------------------------------------------------------
// Kernel 2: fused logits + per-row KL.
// One 256-thread block per row (b,n); 4 samples per thread (S=1024).
// FAST=1: gather bf16 key rows from ws; FAST=0: strided gather from原 layout.
// ---------------------------------------------------------------------------
template<int FAST>
__global__ __launch_bounds__(256)
void affinity_kernel(const float* __restrict__ key_f,
                     const float* __restrict__ query_f,
                     const int*   __restrict__ seg32,
                     const int*   __restrict__ inds,
                     const uint8_t* __restrict__ key8,
                     const float* __restrict__ qt,
                     const uint8_t* __restrict__ seg8,
                     float* __restrict__ out,
                     float* __restrict__ ws_kl,
                     int N, int S, float scale)
{
    const int bid = blockIdx.x;            // b*N + n
    const int tid = threadIdx.x;
    const int b   = bid / N;

    __shared__ float q_lds[CDIM];
    __shared__ float redA[4], redB[4], redC[4];

    if (tid < CDIM) {
        if (FAST) q_lds[tid] = qt[(size_t)bid * CDIM + tid];
        else {
            int n = bid - b * N;
            q_lds[tid] = query_f[((size_t)(b * CDIM + tid)) * N + n];
        }
    }
    const int seg_n = FAST ? (int)seg8[bid] : seg32[bid];
    __syncthreads();

    float q[CDIM];
#pragma unroll
    for (int c = 0; c < CDIM; ++c) q[c] = q_lds[c];

    const size_t rowbase = (size_t)bid * S;
    const int4 iv = ((const int4*)(inds + rowbase))[tid];   // s = 4*tid..4*tid+3
    const int idxv[4] = {iv.x, iv.y, iv.z, iv.w};

    float lg[4];
    int   tf[4];

    if (FAST) {
        // Issue all 16 dwordx4 gathers up front for memory-level parallelism.
        uint4 kd[4][4];
#pragma unroll
        for (int k = 0; k < 4; ++k) {
            const uint4* kr = (const uint4*)(key8 + (((size_t)(b * N + idxv[k])) << 6));
#pragma unroll
            for (int j = 0; j < 4; ++j) kd[k][j] = kr[j];
        }
#pragma unroll
        for (int k = 0; k < 4; ++k) {
            tf[k] = ((int)seg8[b * N + idxv[k]] == seg_n) ? 1 : 0;
            float acc = 0.f;
#pragma unroll
            for (int j = 0; j < 4; ++j) {
                uint32_t uu[4] = {kd[k][j].x, kd[k][j].y, kd[k][j].z, kd[k][j].w};
#pragma unroll
                for (int t = 0; t < 4; ++t) {
                    float flo = __uint_as_float(uu[t] << 16);          // elem c
                    float fhi = __uint_as_float(uu[t] & 0xffff0000u);  // elem c+1
                    int c = j * 8 + t * 2;
                    acc = fmaf(flo, q[c], acc);
                    acc = fmaf(fhi, q[c + 1], acc);
                }
            }
            lg[k] = acc * scale;
        }
    } else {
#pragma unroll
        for (int k = 0; k < 4; ++k) {
            int idx = idxv[k];
            tf[k] = (seg32[b * N + idx] == seg_n) ? 1 : 0;
            float acc = 0.f;
#pragma unroll
            for (int c = 0; c < CDIM; ++c)
                acc = fmaf(key_f[((size_t)(b * CDIM + c)) * N + idx], q[c], acc);
            lg[k] = acc * scale;
        }
    }

    // write logits (coalesced float4)
    ((float4*)(out + rowbase))[tid] = make_float4(lg[0], lg[1], lg[2], lg[3]);

    const int lane = tid & 63, wv = tid >> 6;

    // ---- row max ----
    float m = fmaxf(fmaxf(lg[0], lg[1]), fmaxf(lg[2], lg[3]));
#pragma unroll
    for (int off = 32; off >= 1; off >>= 1)
        m = fmaxf(m, __shfl_xor(m, off, 64));
    if (lane == 0) redA[wv] = m;
    __syncthreads();
    m = fmaxf(fmaxf(redA[0], redA[1]), fmaxf(redA[2], redA[3]));

    // ---- Z = sum exp, T = sum targets ----
    float e[4];
    float z = 0.f, tcnt = 0.f;
#pragma unroll
    for (int k = 0; k < 4; ++k) {
        e[k] = expf(lg[k] - m);
        z += e[k];
        tcnt += (float)tf[k];
    }
#pragma unroll
    for (int off = 32; off >= 1; off >>= 1) {
        z    += __shfl_xor(z, off, 64);
        tcnt += __shfl_xor(tcnt, off, 64);
    }
    if (lane == 0) { redB[wv] = z; redC[wv] = tcnt; }
    __syncthreads();
    const float Z = redB[0] + redB[1] + redB[2] + redB[3];
    const float T = redC[0] + redC[1] + redC[2] + redC[3];

    // ---- KL contribution (rows with seg==0 are masked out entirely) ----
    float kl = 0.f;
    if (seg_n != 0) {
        const float invZ = 1.f / (Z + 1e-9f);
        const float invT = 1.f / (T + 1e-9f);   // y_true for target samples
        const float nlT  = -logf(T + 1e-9f);    // log(y_true)
#pragma unroll
        for (int k = 0; k < 4; ++k) {
            if (tf[k]) {
                float p = e[k] * invZ;
                float yp = logf(fmaxf(p, 1e-8f));
                kl += invT * (nlT - yp);
            }
        }
    }
#pragma unroll
    for (int off = 32; off >= 1; off >>= 1)
        kl += __shfl_xor(kl, off, 64);
    if (lane == 0) redA[wv] = kl;   // safe: all redA reads happened before prior barrier
    __syncthreads();
    if (tid == 0)
        ws_kl[bid] = redA[0] + redA[1] + redA[2] + redA[3];
}

// ---------------------------------------------------------------------------
// Kernel 3: deterministic single-block loss reduction.
// loss = sum(kl_row) / (count(seg!=0) + 1e-9)
// ---------------------------------------------------------------------------
__global__ __launch_bounds__(256)
void loss_reduce(const float* __restrict__ ws_kl,
                 const int* __restrict__ seg32,
                 float* __restrict__ out_loss, int rows)
{
    const int tid = threadIdx.x;
    float s = 0.f, c = 0.f;
    for (int i = tid; i < rows; i += 256) {
        s += ws_kl[i];
        c += (seg32[i] != 0) ? 1.f : 0.f;
    }
#pragma unroll
    for (int off = 32; off >= 1; off >>= 1) {
        s += __shfl_xor(s, off, 64);
        c += __shfl_xor(c, off, 64);
    }
    __shared__ float sA[4], sB[4];
    const int lane = tid & 63, wv = tid >> 6;
    if (lane == 0) { sA[wv] = s; sB[wv] = c; }
    __syncthreads();
    if (tid == 0) {
        float ts = sA[0] + sA[1] + sA[2] + sA[3];
        float tc = sB[0] + sB[1] + sB[2] + sB[3];
        out_loss[0] = ts / (tc + 1e-9f);
    }
}

// ---------------------------------------------------------------------------
extern "C" void kernel_launch(void* const* d_in, const int* in_sizes, int n_in,
                              void* d_out, int out_size, void* d_ws, size_t ws_size,
                              hipStream_t stream)
{
    const float* key_f   = (const float*)d_in[0];
    const float* query_f = (const float*)d_in[1];
    const int*   seg32   = (const int*)d_in[2];
    const int*   inds    = (const int*)d_in[3];
    float* out = (float*)d_out;

    const int N    = NPIX;
    const int rows = in_sizes[2];            // B*N = 32768
    const int S    = in_sizes[3] / rows;     // 1024
    const float scale = (float)(1.0 / sqrt((double)CDIM));

    // ws layout: key8 bf16 rows | qt f32 rows | seg8 | kl array
    const size_t sz_key  = (size_t)rows * CDIM * 2;
    const size_t off_qt  = sz_key;
    const size_t sz_qt   = (size_t)rows * CDIM * 4;
    const size_t off_s8  = off_qt + sz_qt;
    const size_t off_kl  = (off_s8 + (size_t)rows + 255) & ~(size_t)255;
    const size_t need    = off_kl + (size_t)rows * 4;

    uint8_t* wsb = (uint8_t*)d_ws;

    if (ws_size >= need) {
        uint8_t* key8 = wsb;
        float*   qt   = (float*)(wsb + off_qt);
        uint8_t* seg8 = wsb + off_s8;
        float*   wskl = (float*)(wsb + off_kl);

        prep_kernel<<<(rows + 255) / 256, 256, 0, stream>>>(
            key_f, query_f, seg32, key8, qt, seg8, N, rows);
        affinity_kernel<1><<<rows, 256, 0, stream>>>(
            key_f, query_f, seg32, inds, key8, qt, seg8, out, wskl, N, S, scale);
        loss_reduce<<<1, 256, 0, stream>>>(wskl, seg32, out + (size_t)rows * S, rows);
    } else {
        // fallback: no transpose scratch; only needs rows*4 bytes for kl
        float* wskl = (float*)d_ws;
        affinity_kernel<0><<<rows, 256, 0, stream>>>(
            key_f, query_f, seg32, inds, nullptr, nullptr, nullptr, out, wskl, N, S, scale);
        loss_reduce<<<1, 256, 0, stream>>>(wskl, seg32, out + (size_t)rows * S, rows);
    }
}

// Round 4
// 261.633 us; speedup vs baseline: 1.7402x; 1.7402x over previous
//
#include <hip/hip_runtime.h>
#include <stdint.h>

static constexpr int CDIM = 32;     // channels
static constexpr int NPIX = 16384;  // H*W = 128*128
static constexpr int SSAM = 1024;   // samples per row

__device__ __forceinline__ uint32_t f2bf(float f) {
    uint32_t u = __float_as_uint(f);
    return (u + 0x7fffu + ((u >> 16) & 1u)) >> 16;
}

// ---------------------------------------------------------------------------
// Kernel 1: layout prep.
//   key_feat  [B][C][N] f32  -> key8 [B*N][32] bf16 rows (64B, line-aligned)
//   query_feat[B][C][N] f32  -> qt   [B*N][32] f32 rows
//   seg32     [B*N] i32      -> seg8 [B*N] u8
// ---------------------------------------------------------------------------
__global__ __launch_bounds__(256)
void prep_kernel(const float* __restrict__ key_f,
                 const float* __restrict__ query_f,
                 const int* __restrict__ seg32,
                 uint8_t* __restrict__ key8,
                 float* __restrict__ qt,
                 uint8_t* __restrict__ seg8,
                 int N, int rows)
{
    int g = blockIdx.x * 256 + threadIdx.x;
    if (g >= rows) return;
    int b = g / N, n = g - b * N;
    const size_t cb = (size_t)b * CDIM;

    uint32_t packed[16];
#pragma unroll
    for (int c = 0; c < CDIM; c += 2) {
        float f0 = key_f[(cb + c) * N + n];
        float f1 = key_f[(cb + c + 1) * N + n];
        packed[c >> 1] = f2bf(f0) | (f2bf(f1) << 16);
    }
    uint4* kout = (uint4*)(key8 + ((size_t)g << 6));
#pragma unroll
    for (int j = 0; j < 4; ++j)
        kout[j] = make_uint4(packed[4*j], packed[4*j+1], packed[4*j+2], packed[4*j+3]);

    float4* qout = (float4*)(qt + (size_t)g * CDIM);
#pragma unroll
    for (int c = 0; c < CDIM; c += 4) {
        float4 v;
        v.x = query_f[(cb + c    ) * N + n];
        v.y = query_f[(cb + c + 1) * N + n];
        v.z = query_f[(cb + c + 2) * N + n];
        v.w = query_f[(cb + c + 3) * N + n];
        qout[c >> 2] = v;
    }
    seg8[g] = (uint8_t)seg32[g];
}

// ---------------------------------------------------------------------------
// Kernel 2 (fast): cooperative-gather fused logits + per-row KL.
// One 256-thread block per row. 4 lanes per sample: lane sub loads 16B of the
// 64B bf16 key row (contiguous within the group -> coalesced), dots 8
// channels, 2x shfl_xor group reduce. 16 iterations x 16 groups per wave.
// Fixed geometry: N=16384, S=1024, C=32.
// ---------------------------------------------------------------------------
__global__ __launch_bounds__(256)
void affinity_coop(const int*    __restrict__ inds,
                   const uint8_t* __restrict__ key8,
                   const float*  __restrict__ qt,
                   const uint8_t* __restrict__ seg8,
                   float* __restrict__ out,
                   float* __restrict__ ws_kl,
                   float scale)
{
    const int bid  = blockIdx.x;           // b*N + n
    const int tid  = threadIdx.x;
    const int b    = bid >> 14;            // N = 16384
    const int lane = tid & 63;
    const int w    = tid >> 6;             // wave 0..3
    const int g    = lane >> 2;            // group 0..15
    const int sub  = lane & 3;             // 0..3

    __shared__ int   idx_lds[SSAM];
    __shared__ float redA[4], redB[4], redC[4];

    const size_t rowbase = (size_t)bid * SSAM;

    // stage sample indices (coalesced int4)
    ((int4*)idx_lds)[tid] = ((const int4*)(inds + rowbase))[tid];

    // query registers: 8 channels for this sub-lane
    float q[8];
    {
        const float4* qp = (const float4*)(qt + (size_t)bid * CDIM + sub * 8);
        float4 a = qp[0], c = qp[1];
        q[0]=a.x; q[1]=a.y; q[2]=a.z; q[3]=a.w;
        q[4]=c.x; q[5]=c.y; q[6]=c.z; q[7]=c.w;
    }
    const int seg_n = (int)seg8[bid];
    __syncthreads();

    const uint8_t* kb = key8 + ((size_t)b << 20);   // b * N * 64
    const uint8_t* sb = seg8 + ((size_t)b << 14);   // b * N

    float lg[16];
    int   tf_bits = 0;                 // bit i set iff owned sample i is target
    float m = -1e30f;

#pragma unroll
    for (int i = 0; i < 16; ++i) {
        const int s   = (w << 8) + (i << 4) + g;    // sample index in row
        const int idx = idx_lds[s];
        const uint4 kd = *(const uint4*)(kb + ((size_t)idx << 6) + (sub << 4));
        float acc = 0.f;
        uint32_t uu[4] = {kd.x, kd.y, kd.z, kd.w};
#pragma unroll
        for (int t = 0; t < 4; ++t) {
            acc = fmaf(__uint_as_float(uu[t] << 16),         q[2*t],     acc);
            acc = fmaf(__uint_as_float(uu[t] & 0xffff0000u), q[2*t + 1], acc);
        }
        // 4-lane group reduce (butterfly so all 4 lanes hold the dot)
        acc += __shfl_xor(acc, 1, 64);
        acc += __shfl_xor(acc, 2, 64);
        const float v = acc * scale;
        lg[i] = v;
        m = fmaxf(m, v);
        if (sub == (i & 3)) {                       // one lane owns the target flag
            if ((int)sb[idx] == seg_n) tf_bits |= (1 << i);
        }
        if (sub == 0) out[rowbase + s] = v;         // 16 contiguous floats/inst
    }

    // ---- row max ----
#pragma unroll
    for (int off = 32; off >= 1; off >>= 1)
        m = fmaxf(m, __shfl_xor(m, off, 64));
    if (lane == 0) redA[w] = m;
    __syncthreads();
    m = fmaxf(fmaxf(redA[0], redA[1]), fmaxf(redA[2], redA[3]));

    // ---- Z = sum exp (x4 duplicated -> *0.25), T = target count (exact) ----
    float e[16];
    float z = 0.f;
    float tcnt = (float)__popc(tf_bits);
#pragma unroll
    for (int i = 0; i < 16; ++i) {
        e[i] = expf(lg[i] - m);
        z += e[i];
    }
    z *= 0.25f;
#pragma unroll
    for (int off = 32; off >= 1; off >>= 1) {
        z    += __shfl_xor(z, off, 64);
        tcnt += __shfl_xor(tcnt, off, 64);
    }
    if (lane == 0) { redB[w] = z; redC[w] = tcnt; }
    __syncthreads();
    const float Z = redB[0] + redB[1] + redB[2] + redB[3];
    const float T = redC[0] + redC[1] + redC[2] + redC[3];

    // ---- KL contribution (each owned sample counted exactly once) ----
    float kl = 0.f;
    if (seg_n != 0) {
        const float invZ = 1.f / (Z + 1e-9f);
        const float invT = 1.f / (T + 1e-9f);
        const float nlT  = -logf(T + 1e-9f);
#pragma unroll
        for (int i = 0; i < 16; ++i) {
            if ((tf_bits >> i) & 1) {
                float p  = e[i] * invZ;
                float yp = logf(fmaxf(p, 1e-8f));
                kl += invT * (nlT - yp);
            }
        }
    }
#pragma unroll
    for (int off = 32; off >= 1; off >>= 1)
        kl += __shfl_xor(kl, off, 64);
    if (lane == 0) redA[w] = kl;   // safe: all max-reads of redA preceded sync3
    __syncthreads();
    if (tid == 0)
        ws_kl[bid] = redA[0] + redA[1] + redA[2] + redA[3];
}

// ---------------------------------------------------------------------------
// Fallback (generic shapes / tiny ws): original per-thread gather from the
// native [C][N] layout. Slow but correct.
// ---------------------------------------------------------------------------
__global__ __launch_bounds__(256)
void affinity_fallback(const float* __restrict__ key_f,
                       const float* __restrict__ query_f,
                       const int*   __restrict__ seg32,
                       const int*   __restrict__ inds,
                       float* __restrict__ out,
                       float* __restrict__ ws_kl,
                       int N, int S, float scale)
{
    const int bid = blockIdx.x;
    const int tid = threadIdx.x;
    const int b   = bid / N;

    __shared__ float q_lds[CDIM];
    __shared__ float redA[4], redB[4], redC[4];

    if (tid < CDIM) {
        int n = bid - b * N;
        q_lds[tid] = query_f[((size_t)(b * CDIM + tid)) * N + n];
    }
    const int seg_n = seg32[bid];
    __syncthreads();

    float q[CDIM];
#pragma unroll
    for (int c = 0; c < CDIM; ++c) q[c] = q_lds[c];

    const size_t rowbase = (size_t)bid * S;
    const int4 iv = ((const int4*)(inds + rowbase))[tid];
    const int idxv[4] = {iv.x, iv.y, iv.z, iv.w};

    float lg[4];
    int   tf[4];
#pragma unroll
    for (int k = 0; k < 4; ++k) {
        int idx = idxv[k];
        tf[k] = (seg32[b * N + idx] == seg_n) ? 1 : 0;
        float acc = 0.f;
#pragma unroll
        for (int c = 0; c < CDIM; ++c)
            acc = fmaf(key_f[((size_t)(b * CDIM + c)) * N + idx], q[c], acc);
        lg[k] = acc * scale;
    }
    ((float4*)(out + rowbase))[tid] = make_float4(lg[0], lg[1], lg[2], lg[3]);

    const int lane = tid & 63, wv = tid >> 6;
    float m = fmaxf(fmaxf(lg[0], lg[1]), fmaxf(lg[2], lg[3]));
#pragma unroll
    for (int off = 32; off >= 1; off >>= 1)
        m = fmaxf(m, __shfl_xor(m, off, 64));
    if (lane == 0) redA[wv] = m;
    __syncthreads();
    m = fmaxf(fmaxf(redA[0], redA[1]), fmaxf(redA[2], redA[3]));

    float e[4], z = 0.f, tcnt = 0.f;
#pragma unroll
    for (int k = 0; k < 4; ++k) {
        e[k] = expf(lg[k] - m);
        z += e[k];
        tcnt += (float)tf[k];
    }
#pragma unroll
    for (int off = 32; off >= 1; off >>= 1) {
        z    += __shfl_xor(z, off, 64);
        tcnt += __shfl_xor(tcnt, off, 64);
    }
    if (lane == 0) { redB[wv] = z; redC[wv] = tcnt; }
    __syncthreads();
    const float Z = redB[0] + redB[1] + redB[2] + redB[3];
    const float T = redC[0] + redC[1] + redC[2] + redC[3];

    float kl = 0.f;
    if (seg_n != 0) {
        const float invZ = 1.f / (Z + 1e-9f);
        const float invT = 1.f / (T + 1e-9f);
        const float nlT  = -logf(T + 1e-9f);
#pragma unroll
        for (int k = 0; k < 4; ++k) {
            if (tf[k]) {
                float p = e[k] * invZ;
                float yp = logf(fmaxf(p, 1e-8f));
                kl += invT * (nlT - yp);
            }
        }
    }
#pragma unroll
    for (int off = 32; off >= 1; off >>= 1)
        kl += __shfl_xor(kl, off, 64);
    if (lane == 0) redA[wv] = kl;
    __syncthreads();
    if (tid == 0)
        ws_kl[bid] = redA[0] + redA[1] + redA[2] + redA[3];
}

// ---------------------------------------------------------------------------
// Kernel 3: deterministic single-block loss reduction.
// ---------------------------------------------------------------------------
__global__ __launch_bounds__(256)
void loss_reduce(const float* __restrict__ ws_kl,
                 const int* __restrict__ seg32,
                 float* __restrict__ out_loss, int rows)
{
    const int tid = threadIdx.x;
    float s = 0.f, c = 0.f;
    for (int i = tid; i < rows; i += 256) {
        s += ws_kl[i];
        c += (seg32[i] != 0) ? 1.f : 0.f;
    }
#pragma unroll
    for (int off = 32; off >= 1; off >>= 1) {
        s += __shfl_xor(s, off, 64);
        c += __shfl_xor(c, off, 64);
    }
    __shared__ float sA[4], sB[4];
    const int lane = tid & 63, wv = tid >> 6;
    if (lane == 0) { sA[wv] = s; sB[wv] = c; }
    __syncthreads();
    if (tid == 0) {
        float ts = sA[0] + sA[1] + sA[2] + sA[3];
        float tc = sB[0] + sB[1] + sB[2] + sB[3];
        out_loss[0] = ts / (tc + 1e-9f);
    }
}

// ---------------------------------------------------------------------------
extern "C" void kernel_launch(void* const* d_in, const int* in_sizes, int n_in,
                              void* d_out, int out_size, void* d_ws, size_t ws_size,
                              hipStream_t stream)
{
    const float* key_f   = (const float*)d_in[0];
    const float* query_f = (const float*)d_in[1];
    const int*   seg32   = (const int*)d_in[2];
    const int*   inds    = (const int*)d_in[3];
    float* out = (float*)d_out;

    const int N    = NPIX;
    const int rows = in_sizes[2];            // B*N
    const int S    = in_sizes[3] / rows;     // 1024
    const float scale = (float)(1.0 / sqrt((double)CDIM));

    // ws layout: key8 bf16 rows | qt f32 rows | seg8 | kl array
    const size_t sz_key  = (size_t)rows * CDIM * 2;
    const size_t off_qt  = sz_key;
    const size_t sz_qt   = (size_t)rows * CDIM * 4;
    const size_t off_s8  = off_qt + sz_qt;
    const size_t off_kl  = (off_s8 + (size_t)rows + 255) & ~(size_t)255;
    const size_t need    = off_kl + (size_t)rows * 4;

    uint8_t* wsb = (uint8_t*)d_ws;

    const bool geom_ok = (S == SSAM) && (rows % N == 0);

    if (ws_size >= need && geom_ok) {
        uint8_t* key8 = wsb;
        float*   qt   = (float*)(wsb + off_qt);
        uint8_t* seg8 = wsb + off_s8;
        float*   wskl = (float*)(wsb + off_kl);

        prep_kernel<<<(rows + 255) / 256, 256, 0, stream>>>(
            key_f, query_f, seg32, key8, qt, seg8, N, rows);
        affinity_coop<<<rows, 256, 0, stream>>>(
            inds, key8, qt, seg8, out, wskl, scale);
        loss_reduce<<<1, 256, 0, stream>>>(wskl, seg32, out + (size_t)rows * S, rows);
    } else {
        float* wskl = (float*)d_ws;
        affinity_fallback<<<rows, 256, 0, stream>>>(
            key_f, query_f, seg32, inds, out, wskl, N, S, scale);
        loss_reduce<<<1, 256, 0, stream>>>(wskl, seg32, out + (size_t)rows * S, rows);
    }
}

// Round 5
// 215.746 us; speedup vs baseline: 2.1103x; 1.2127x over previous
//
#include <hip/hip_runtime.h>
#include <stdint.h>

typedef _Float16 h2 __attribute__((ext_vector_type(2)));

static constexpr int CDIM = 32;     // channels
static constexpr int NPIX = 16384;  // H*W
static constexpr int SSAM = 1024;   // samples per row

__device__ __forceinline__ uint16_t f2h(float f) {
    union { _Float16 h; uint16_t u; } c;
    c.h = (_Float16)f;
    return c.u;
}

// cross-lane add via DPP quad_perm (VALU-only, no LDS pipe).
// xor1: quad_perm [1,0,3,2] = 0xB1 ; xor2: quad_perm [2,3,0,1] = 0x4E
template<int CTRL>
__device__ __forceinline__ float dpp_add(float x) {
    int y = __builtin_amdgcn_mov_dpp(__float_as_int(x), CTRL, 0xF, 0xF, true);
    return x + __int_as_float(y);
}

__device__ __forceinline__ float dot2(h2 a, h2 b, float c) {
    return __builtin_amdgcn_fdot2(a, b, c, false);   // v_dot2_f32_f16
}

// ---------------------------------------------------------------------------
// Kernel 1: layout prep.
//   key_feat  [B][C][N] f32 -> key16 [B*N][32] f16 rows (64B, line-aligned)
//   query_feat[B][C][N] f32 -> q16   [B*N][32] f16 rows, PRE-SCALED by C^-0.5
//   seg32     [B*N] i32     -> seg8  [B*N] u8
// ---------------------------------------------------------------------------
__global__ __launch_bounds__(256)
void prep_kernel(const float* __restrict__ key_f,
                 const float* __restrict__ query_f,
                 const int* __restrict__ seg32,
                 uint8_t* __restrict__ key16,
                 uint8_t* __restrict__ q16,
                 uint8_t* __restrict__ seg8,
                 int N, int rows, float scale)
{
    int gI = blockIdx.x * 256 + threadIdx.x;
    if (gI >= rows) return;
    int b = gI / N, n = gI - b * N;
    const size_t cb = (size_t)b * CDIM;

    uint32_t kp[16], qp[16];
#pragma unroll
    for (int c = 0; c < CDIM; c += 2) {
        float k0 = key_f[(cb + c) * N + n];
        float k1 = key_f[(cb + c + 1) * N + n];
        float q0 = query_f[(cb + c) * N + n] * scale;
        float q1 = query_f[(cb + c + 1) * N + n] * scale;
        kp[c >> 1] = (uint32_t)f2h(k0) | ((uint32_t)f2h(k1) << 16);
        qp[c >> 1] = (uint32_t)f2h(q0) | ((uint32_t)f2h(q1) << 16);
    }
    uint4* ko = (uint4*)(key16 + ((size_t)gI << 6));
    uint4* qo = (uint4*)(q16 + ((size_t)gI << 6));
#pragma unroll
    for (int j = 0; j < 4; ++j) {
        ko[j] = make_uint4(kp[4*j], kp[4*j+1], kp[4*j+2], kp[4*j+3]);
        qo[j] = make_uint4(qp[4*j], qp[4*j+1], qp[4*j+2], qp[4*j+3]);
    }
    seg8[gI] = (uint8_t)seg32[gI];
}

// ---------------------------------------------------------------------------
// Kernel 2 (fast): cooperative-gather fused logits + per-row KL.
// 4 lanes per sample (contiguous 16B each of the 64B f16 key row -> 1 line
// per sample). v_dot2_f32_f16 inner product, DPP group reduce. Batch seg
// array (16KB) staged in LDS; divergent seg lookups go to the LDS pipe.
// Sample i owned by lane sub==(i&3): exp/log computed once per sample.
// Fixed geometry: N=16384, S=1024, C=32.
// ---------------------------------------------------------------------------
__global__ __launch_bounds__(256)
void affinity_coop(const int* __restrict__ inds,
                   const uint8_t* __restrict__ key16,
                   const uint8_t* __restrict__ q16,
                   const uint8_t* __restrict__ seg8,
                   float* __restrict__ out,
                   float* __restrict__ ws_kl)
{
    const int bid  = blockIdx.x;           // b*N + n
    const int tid  = threadIdx.x;
    const int b    = bid >> 14;            // N = 16384
    const int lane = tid & 63;
    const int w    = tid >> 6;             // wave 0..3
    const int g    = lane >> 2;            // group 0..15
    const int sub  = lane & 3;             // quarter 0..3

    __shared__ __align__(16) int     idx_lds[SSAM];
    __shared__ __align__(16) uint8_t seg_lds[NPIX];   // 16KB: whole batch seg
    __shared__ float redA[4], redB[4], redC[4];

    const size_t rowbase = (size_t)bid * SSAM;

    // stage sample indices (coalesced int4)
    ((int4*)idx_lds)[tid] = ((const int4*)(inds + rowbase))[tid];

    // stage seg bytes for batch b (coalesced uint4, 4 rounds)
    const uint8_t* sbg = seg8 + ((size_t)b << 14);
#pragma unroll
    for (int r = 0; r < 4; ++r)
        ((uint4*)seg_lds)[(r << 8) + tid] = ((const uint4*)sbg)[(r << 8) + tid];

    // query fragment: 8 channels (4 half2) for this sub-lane, pre-scaled
    h2 qh[4];
    {
        union { uint4 u; h2 h[4]; } qc;
        qc.u = *(const uint4*)(q16 + ((size_t)bid << 6) + (sub << 4));
        qh[0] = qc.h[0]; qh[1] = qc.h[1]; qh[2] = qc.h[2]; qh[3] = qc.h[3];
    }
    __syncthreads();

    const int seg_n = (int)seg_lds[bid & 0x3FFF];
    const uint8_t* kb = key16 + ((size_t)b << 20);    // b * N * 64
    const uint32_t subs = (uint32_t)(sub << 4);

    float lgo[4];                  // owned logits (i = 4j + sub)
    int   tfm = 0;                 // owned target bits j=0..3
    float m = -1e30f;

#pragma unroll
    for (int i = 0; i < 16; ++i) {
        const int s   = (w << 8) + (i << 4) + g;
        const int idx = idx_lds[s];
        union { uint4 u; h2 h[4]; } kc;
        kc.u = *(const uint4*)(kb + (((uint32_t)idx << 6) | subs));
        float acc = dot2(kc.h[0], qh[0], 0.f);
        acc = dot2(kc.h[1], qh[1], acc);
        acc = dot2(kc.h[2], qh[2], acc);
        acc = dot2(kc.h[3], qh[3], acc);
        acc = dpp_add<0xB1>(acc);          // xor 1
        acc = dpp_add<0x4E>(acc);          // xor 2 -> all 4 lanes hold dot
        m = fmaxf(m, acc);
        if (sub == (i & 3)) {              // owner lane for this sample
            lgo[i >> 2] = acc;
            if ((int)seg_lds[idx] == seg_n) tfm |= 1 << (i >> 2);
        }
        if (sub == 0) out[rowbase + s] = acc;   // 16 contiguous floats
    }

    // ---- row max ----
#pragma unroll
    for (int off = 32; off >= 1; off >>= 1)
        m = fmaxf(m, __shfl_xor(m, off, 64));
    if (lane == 0) redA[w] = m;
    __syncthreads();
    m = fmaxf(fmaxf(redA[0], redA[1]), fmaxf(redA[2], redA[3]));

    // ---- Z = sum exp (each sample exactly once), T = target count ----
    float e[4];
    float z = 0.f, tcnt = (float)__popc((unsigned)tfm);
#pragma unroll
    for (int j = 0; j < 4; ++j) {
        e[j] = __expf(lgo[j] - m);
        z += e[j];
    }
#pragma unroll
    for (int off = 32; off >= 1; off >>= 1) {
        z    += __shfl_xor(z, off, 64);
        tcnt += __shfl_xor(tcnt, off, 64);
    }
    if (lane == 0) { redB[w] = z; redC[w] = tcnt; }
    __syncthreads();
    const float Z = redB[0] + redB[1] + redB[2] + redB[3];
    const float T = redC[0] + redC[1] + redC[2] + redC[3];

    // ---- KL contribution ----
    float kl = 0.f;
    if (seg_n != 0) {
        const float invZ = 1.f / (Z + 1e-9f);
        const float invT = 1.f / (T + 1e-9f);
        const float nlT  = -__logf(T + 1e-9f);
#pragma unroll
        for (int j = 0; j < 4; ++j) {
            if ((tfm >> j) & 1) {
                float p  = e[j] * invZ;
                float yp = __logf(fmaxf(p, 1e-8f));
                kl += invT * (nlT - yp);
            }
        }
    }
#pragma unroll
    for (int off = 32; off >= 1; off >>= 1)
        kl += __shfl_xor(kl, off, 64);
    if (lane == 0) redA[w] = kl;   // safe: redA(max) reads preceded sync2
    __syncthreads();
    if (tid == 0)
        ws_kl[bid] = redA[0] + redA[1] + redA[2] + redA[3];
}

// ---------------------------------------------------------------------------
// Fallback (generic shapes / tiny ws): per-thread gather from native layout.
// ---------------------------------------------------------------------------
__global__ __launch_bounds__(256)
void affinity_fallback(const float* __restrict__ key_f,
                       const float* __restrict__ query_f,
                       const int*   __restrict__ seg32,
                       const int*   __restrict__ inds,
                       float* __restrict__ out,
                       float* __restrict__ ws_kl,
                       int N, int S, float scale)
{
    const int bid = blockIdx.x;
    const int tid = threadIdx.x;
    const int b   = bid / N;

    __shared__ float q_lds[CDIM];
    __shared__ float redA[4], redB[4], redC[4];

    if (tid < CDIM) {
        int n = bid - b * N;
        q_lds[tid] = query_f[((size_t)(b * CDIM + tid)) * N + n];
    }
    const int seg_n = seg32[bid];
    __syncthreads();

    float q[CDIM];
#pragma unroll
    for (int c = 0; c < CDIM; ++c) q[c] = q_lds[c];

    const size_t rowbase = (size_t)bid * S;
    const int4 iv = ((const int4*)(inds + rowbase))[tid];
    const int idxv[4] = {iv.x, iv.y, iv.z, iv.w};

    float lg[4];
    int   tf[4];
#pragma unroll
    for (int k = 0; k < 4; ++k) {
        int idx = idxv[k];
        tf[k] = (seg32[b * N + idx] == seg_n) ? 1 : 0;
        float acc = 0.f;
#pragma unroll
        for (int c = 0; c < CDIM; ++c)
            acc = fmaf(key_f[((size_t)(b * CDIM + c)) * N + idx], q[c], acc);
        lg[k] = acc * scale;
    }
    ((float4*)(out + rowbase))[tid] = make_float4(lg[0], lg[1], lg[2], lg[3]);

    const int lane = tid & 63, wv = tid >> 6;
    float m = fmaxf(fmaxf(lg[0], lg[1]), fmaxf(lg[2], lg[3]));
#pragma unroll
    for (int off = 32; off >= 1; off >>= 1)
        m = fmaxf(m, __shfl_xor(m, off, 64));
    if (lane == 0) redA[wv] = m;
    __syncthreads();
    m = fmaxf(fmaxf(redA[0], redA[1]), fmaxf(redA[2], redA[3]));

    float e[4], z = 0.f, tcnt = 0.f;
#pragma unroll
    for (int k = 0; k < 4; ++k) {
        e[k] = expf(lg[k] - m);
        z += e[k];
        tcnt += (float)tf[k];
    }
#pragma unroll
    for (int off = 32; off >= 1; off >>= 1) {
        z    += __shfl_xor(z, off, 64);
        tcnt += __shfl_xor(tcnt, off, 64);
    }
    if (lane == 0) { redB[wv] = z; redC[wv] = tcnt; }
    __syncthreads();
    const float Z = redB[0] + redB[1] + redB[2] + redB[3];
    const float T = redC[0] + redC[1] + redC[2] + redC[3];

    float kl = 0.f;
    if (seg_n != 0) {
        const float invZ = 1.f / (Z + 1e-9f);
        const float invT = 1.f / (T + 1e-9f);
        const float nlT  = -logf(T + 1e-9f);
#pragma unroll
        for (int k = 0; k < 4; ++k) {
            if (tf[k]) {
                float p = e[k] * invZ;
                float yp = logf(fmaxf(p, 1e-8f));
                kl += invT * (nlT - yp);
            }
        }
    }
#pragma unroll
    for (int off = 32; off >= 1; off >>= 1)
        kl += __shfl_xor(kl, off, 64);
    if (lane == 0) redA[wv] = kl;
    __syncthreads();
    if (tid == 0)
        ws_kl[bid] = redA[0] + redA[1] + redA[2] + redA[3];
}

// ---------------------------------------------------------------------------
// Kernel 3: deterministic single-block loss reduction.
// ---------------------------------------------------------------------------
__global__ __launch_bounds__(256)
void loss_reduce(const float* __restrict__ ws_kl,
                 const int* __restrict__ seg32,
                 float* __restrict__ out_loss, int rows)
{
    const int tid = threadIdx.x;
    float s = 0.f, c = 0.f;
    for (int i = tid; i < rows; i += 256) {
        s += ws_kl[i];
        c += (seg32[i] != 0) ? 1.f : 0.f;
    }
#pragma unroll
    for (int off = 32; off >= 1; off >>= 1) {
        s += __shfl_xor(s, off, 64);
        c += __shfl_xor(c, off, 64);
    }
    __shared__ float sA[4], sB[4];
    const int lane = tid & 63, wv = tid >> 6;
    if (lane == 0) { sA[wv] = s; sB[wv] = c; }
    __syncthreads();
    if (tid == 0) {
        float ts = sA[0] + sA[1] + sA[2] + sA[3];
        float tc = sB[0] + sB[1] + sB[2] + sB[3];
        out_loss[0] = ts / (tc + 1e-9f);
    }
}

// ---------------------------------------------------------------------------
extern "C" void kernel_launch(void* const* d_in, const int* in_sizes, int n_in,
                              void* d_out, int out_size, void* d_ws, size_t ws_size,
                              hipStream_t stream)
{
    const float* key_f   = (const float*)d_in[0];
    const float* query_f = (const float*)d_in[1];
    const int*   seg32   = (const int*)d_in[2];
    const int*   inds    = (const int*)d_in[3];
    float* out = (float*)d_out;

    const int N    = NPIX;
    const int rows = in_sizes[2];            // B*N
    const int S    = in_sizes[3] / rows;     // 1024
    const float scale = (float)(1.0 / sqrt((double)CDIM));

    // ws layout: key16 rows | q16 rows | seg8 | kl array
    const size_t off_q16 = (size_t)rows * 64;
    const size_t off_s8  = off_q16 + (size_t)rows * 64;
    const size_t off_kl  = (off_s8 + (size_t)rows + 255) & ~(size_t)255;
    const size_t need    = off_kl + (size_t)rows * 4;

    uint8_t* wsb = (uint8_t*)d_ws;
    const bool geom_ok = (S == SSAM) && (rows % N == 0);

    if (ws_size >= need && geom_ok) {
        uint8_t* key16 = wsb;
        uint8_t* q16   = wsb + off_q16;
        uint8_t* seg8  = wsb + off_s8;
        float*   wskl  = (float*)(wsb + off_kl);

        prep_kernel<<<(rows + 255) / 256, 256, 0, stream>>>(
            key_f, query_f, seg32, key16, q16, seg8, N, rows, scale);
        affinity_coop<<<rows, 256, 0, stream>>>(
            inds, key16, q16, seg8, out, wskl);
        loss_reduce<<<1, 256, 0, stream>>>(wskl, seg32, out + (size_t)rows * S, rows);
    } else {
        float* wskl = (float*)d_ws;
        affinity_fallback<<<rows, 256, 0, stream>>>(
            key_f, query_f, seg32, inds, out, wskl, N, S, scale);
        loss_reduce<<<1, 256, 0, stream>>>(wskl, seg32, out + (size_t)rows * S, rows);
    }
}

// Round 6
// 190.208 us; speedup vs baseline: 2.3937x; 1.1343x over previous
//
#include <hip/hip_runtime.h>
#include <stdint.h>

typedef _Float16 h2 __attribute__((ext_vector_type(2)));

static constexpr int CDIM = 32;     // channels
static constexpr int NPIX = 16384;  // H*W
static constexpr int SSAM = 1024;   // samples per row

__device__ __forceinline__ uint16_t f2h(float f) {
    union { _Float16 h; uint16_t u; } c;
    c.h = (_Float16)f;
    return c.u;
}

// cross-lane add via DPP quad_perm (VALU-only, no LDS pipe).
// xor1: quad_perm [1,0,3,2] = 0xB1 ; xor2: quad_perm [2,3,0,1] = 0x4E
template<int CTRL>
__device__ __forceinline__ float dpp_add(float x) {
    int y = __builtin_amdgcn_mov_dpp(__float_as_int(x), CTRL, 0xF, 0xF, true);
    return x + __int_as_float(y);
}

__device__ __forceinline__ float dot2(h2 a, h2 b, float c) {
    return __builtin_amdgcn_fdot2(a, b, c, false);   // v_dot2_f32_f16
}

// ---------------------------------------------------------------------------
// Kernel 1: layout prep.
//   key_feat  [B][C][N] f32 -> key16 [B*N][32] f16 rows (64B, line-aligned)
//   query_feat[B][C][N] f32 -> q16   [B*N][32] f16 rows, PRE-SCALED by C^-0.5
//   seg32     [B*N] i32     -> seg8  [B*N] u8
// ---------------------------------------------------------------------------
__global__ __launch_bounds__(256)
void prep_kernel(const float* __restrict__ key_f,
                 const float* __restrict__ query_f,
                 const int* __restrict__ seg32,
                 uint8_t* __restrict__ key16,
                 uint8_t* __restrict__ q16,
                 uint8_t* __restrict__ seg8,
                 int N, int rows, float scale)
{
    int gI = blockIdx.x * 256 + threadIdx.x;
    if (gI >= rows) return;
    int b = gI / N, n = gI - b * N;
    const size_t cb = (size_t)b * CDIM;

    uint32_t kp[16], qp[16];
#pragma unroll
    for (int c = 0; c < CDIM; c += 2) {
        float k0 = key_f[(cb + c) * N + n];
        float k1 = key_f[(cb + c + 1) * N + n];
        float q0 = query_f[(cb + c) * N + n] * scale;
        float q1 = query_f[(cb + c + 1) * N + n] * scale;
        kp[c >> 1] = (uint32_t)f2h(k0) | ((uint32_t)f2h(k1) << 16);
        qp[c >> 1] = (uint32_t)f2h(q0) | ((uint32_t)f2h(q1) << 16);
    }
    uint4* ko = (uint4*)(key16 + ((size_t)gI << 6));
    uint4* qo = (uint4*)(q16 + ((size_t)gI << 6));
#pragma unroll
    for (int j = 0; j < 4; ++j) {
        ko[j] = make_uint4(kp[4*j], kp[4*j+1], kp[4*j+2], kp[4*j+3]);
        qo[j] = make_uint4(qp[4*j], qp[4*j+1], qp[4*j+2], qp[4*j+3]);
    }
    seg8[gI] = (uint8_t)seg32[gI];
}

// ---------------------------------------------------------------------------
// Kernel 2 (fast): cooperative-gather fused logits + per-row KL.
// 4 lanes per sample; 3-phase unrolled body: (1) 16 idx LDS reads,
// (2) 16 in-flight dwordx4 key gathers (64 VGPRs — occupancy is LDS-limited
// at 7 blocks/CU so registers are free), (3) dot2 + DPP reduce + store.
// Divergent seg lookups moved to a 4-iter owner-lane loop after the gathers.
// Fixed geometry: N=16384, S=1024, C=32.
// ---------------------------------------------------------------------------
__global__ __launch_bounds__(256)
void affinity_coop(const int* __restrict__ inds,
                   const uint8_t* __restrict__ key16,
                   const uint8_t* __restrict__ q16,
                   const uint8_t* __restrict__ seg8,
                   float* __restrict__ out,
                   float* __restrict__ ws_kl)
{
    const int bid  = blockIdx.x;           // b*N + n
    const int tid  = threadIdx.x;
    const int b    = bid >> 14;            // N = 16384
    const int lane = tid & 63;
    const int w    = tid >> 6;             // wave 0..3
    const int g    = lane >> 2;            // group 0..15
    const int sub  = lane & 3;             // quarter 0..3

    __shared__ __align__(16) int     idx_lds[SSAM];
    __shared__ __align__(16) uint8_t seg_lds[NPIX];   // 16KB: whole batch seg
    __shared__ float redA[4], redB[4], redC[4];

    const size_t rowbase = (size_t)bid * SSAM;

    // stage sample indices (coalesced int4)
    ((int4*)idx_lds)[tid] = ((const int4*)(inds + rowbase))[tid];

    // stage seg bytes for batch b (coalesced uint4, 4 rounds)
    const uint8_t* sbg = seg8 + ((size_t)b << 14);
#pragma unroll
    for (int r = 0; r < 4; ++r)
        ((uint4*)seg_lds)[(r << 8) + tid] = ((const uint4*)sbg)[(r << 8) + tid];

    // query fragment: 8 channels (4 half2) for this sub-lane, pre-scaled
    h2 qh[4];
    {
        union { uint4 u; h2 h[4]; } qc;
        qc.u = *(const uint4*)(q16 + ((size_t)bid << 6) + (sub << 4));
        qh[0] = qc.h[0]; qh[1] = qc.h[1]; qh[2] = qc.h[2]; qh[3] = qc.h[3];
    }
    __syncthreads();

    const int seg_n = (int)seg_lds[bid & 0x3FFF];
    const uint8_t* kb = key16 + ((size_t)b << 20);    // b * N * 64
    const uint32_t subs = (uint32_t)(sub << 4);
    const int sbase = (w << 8) + g;                   // sample = sbase + i*16

    // ---- phase 1: all 16 indices from LDS (conflict-free broadcast) ----
    int idxs[16];
#pragma unroll
    for (int i = 0; i < 16; ++i)
        idxs[i] = idx_lds[sbase + (i << 4)];

    // ---- phase 2: issue all 16 key gathers (stay in flight together) ----
    uint4 kd[16];
#pragma unroll
    for (int i = 0; i < 16; ++i)
        kd[i] = *(const uint4*)(kb + (((uint32_t)idxs[i] << 6) | subs));

    // ---- phase 3: dots, group reduce, store ----
    float lgo[4];                  // owned logits (i = 4j + sub)
    float m = -1e30f;
#pragma unroll
    for (int i = 0; i < 16; ++i) {
        union { uint4 u; h2 h[4]; } kc; kc.u = kd[i];
        float acc = dot2(kc.h[0], qh[0], 0.f);
        acc = dot2(kc.h[1], qh[1], acc);
        acc = dot2(kc.h[2], qh[2], acc);
        acc = dot2(kc.h[3], qh[3], acc);
        acc = dpp_add<0xB1>(acc);          // xor 1
        acc = dpp_add<0x4E>(acc);          // xor 2 -> all 4 lanes hold dot
        m = fmaxf(m, acc);
        if (sub == (i & 3)) lgo[i >> 2] = acc;       // cndmask, no branch
        if (sub == 0) out[rowbase + sbase + (i << 4)] = acc;  // 64B contig
    }

    // ---- owned-target flags (4 all-lane LDS reads; no in-loop divergence) --
    int tfm = 0;
#pragma unroll
    for (int j = 0; j < 4; ++j) {
        int idx = idx_lds[sbase + ((((j << 2) | sub)) << 4)];
        if ((int)seg_lds[idx] == seg_n) tfm |= 1 << j;
    }

    // ---- row max (values quad-uniform -> 4-step butterfly) ----
#pragma unroll
    for (int off = 32; off >= 4; off >>= 1)
        m = fmaxf(m, __shfl_xor(m, off, 64));
    if (lane == 0) redA[w] = m;
    __syncthreads();
    m = fmaxf(fmaxf(redA[0], redA[1]), fmaxf(redA[2], redA[3]));

    // ---- Z = sum exp (each sample once), T = target count ----
    float e[4];
    float z = 0.f, tcnt = (float)__popc((unsigned)tfm);
#pragma unroll
    for (int j = 0; j < 4; ++j) {
        e[j] = __expf(lgo[j] - m);
        z += e[j];
    }
#pragma unroll
    for (int off = 32; off >= 1; off >>= 1) {
        z    += __shfl_xor(z, off, 64);
        tcnt += __shfl_xor(tcnt, off, 64);
    }
    if (lane == 0) { redB[w] = z; redC[w] = tcnt; }
    __syncthreads();
    const float Z = redB[0] + redB[1] + redB[2] + redB[3];
    const float T = redC[0] + redC[1] + redC[2] + redC[3];

    // ---- KL contribution (seg_n is block-uniform; skip if masked row) ----
    if (seg_n != 0) {
        float kl = 0.f;
        const float invZ = 1.f / (Z + 1e-9f);
        const float invT = 1.f / (T + 1e-9f);
        const float nlT  = -__logf(T + 1e-9f);
#pragma unroll
        for (int j = 0; j < 4; ++j) {
            if ((tfm >> j) & 1) {
                float p  = e[j] * invZ;
                float yp = __logf(fmaxf(p, 1e-8f));
                kl += invT * (nlT - yp);
            }
        }
#pragma unroll
        for (int off = 32; off >= 1; off >>= 1)
            kl += __shfl_xor(kl, off, 64);
        if (lane == 0) redA[w] = kl;
        __syncthreads();
        if (tid == 0)
            ws_kl[bid] = redA[0] + redA[1] + redA[2] + redA[3];
    } else {
        if (tid == 0) ws_kl[bid] = 0.f;
    }
}

// ---------------------------------------------------------------------------
// Fallback (generic shapes / tiny ws): per-thread gather from native layout.
// ---------------------------------------------------------------------------
__global__ __launch_bounds__(256)
void affinity_fallback(const float* __restrict__ key_f,
                       const float* __restrict__ query_f,
                       const int*   __restrict__ seg32,
                       const int*   __restrict__ inds,
                       float* __restrict__ out,
                       float* __restrict__ ws_kl,
                       int N, int S, float scale)
{
    const int bid = blockIdx.x;
    const int tid = threadIdx.x;
    const int b   = bid / N;

    __shared__ float q_lds[CDIM];
    __shared__ float redA[4], redB[4], redC[4];

    if (tid < CDIM) {
        int n = bid - b * N;
        q_lds[tid] = query_f[((size_t)(b * CDIM + tid)) * N + n];
    }
    const int seg_n = seg32[bid];
    __syncthreads();

    float q[CDIM];
#pragma unroll
    for (int c = 0; c < CDIM; ++c) q[c] = q_lds[c];

    const size_t rowbase = (size_t)bid * S;
    const int4 iv = ((const int4*)(inds + rowbase))[tid];
    const int idxv[4] = {iv.x, iv.y, iv.z, iv.w};

    float lg[4];
    int   tf[4];
#pragma unroll
    for (int k = 0; k < 4; ++k) {
        int idx = idxv[k];
        tf[k] = (seg32[b * N + idx] == seg_n) ? 1 : 0;
        float acc = 0.f;
#pragma unroll
        for (int c = 0; c < CDIM; ++c)
            acc = fmaf(key_f[((size_t)(b * CDIM + c)) * N + idx], q[c], acc);
        lg[k] = acc * scale;
    }
    ((float4*)(out + rowbase))[tid] = make_float4(lg[0], lg[1], lg[2], lg[3]);

    const int lane = tid & 63, wv = tid >> 6;
    float m = fmaxf(fmaxf(lg[0], lg[1]), fmaxf(lg[2], lg[3]));
#pragma unroll
    for (int off = 32; off >= 1; off >>= 1)
        m = fmaxf(m, __shfl_xor(m, off, 64));
    if (lane == 0) redA[wv] = m;
    __syncthreads();
    m = fmaxf(fmaxf(redA[0], redA[1]), fmaxf(redA[2], redA[3]));

    float e[4], z = 0.f, tcnt = 0.f;
#pragma unroll
    for (int k = 0; k < 4; ++k) {
        e[k] = expf(lg[k] - m);
        z += e[k];
        tcnt += (float)tf[k];
    }
#pragma unroll
    for (int off = 32; off >= 1; off >>= 1) {
        z    += __shfl_xor(z, off, 64);
        tcnt += __shfl_xor(tcnt, off, 64);
    }
    if (lane == 0) { redB[wv] = z; redC[wv] = tcnt; }
    __syncthreads();
    const float Z = redB[0] + redB[1] + redB[2] + redB[3];
    const float T = redC[0] + redC[1] + redC[2] + redC[3];

    float kl = 0.f;
    if (seg_n != 0) {
        const float invZ = 1.f / (Z + 1e-9f);
        const float invT = 1.f / (T + 1e-9f);
        const float nlT  = -logf(T + 1e-9f);
#pragma unroll
        for (int k = 0; k < 4; ++k) {
            if (tf[k]) {
                float p = e[k] * invZ;
                float yp = logf(fmaxf(p, 1e-8f));
                kl += invT * (nlT - yp);
            }
        }
    }
#pragma unroll
    for (int off = 32; off >= 1; off >>= 1)
        kl += __shfl_xor(kl, off, 64);
    if (lane == 0) redA[wv] = kl;
    __syncthreads();
    if (tid == 0)
        ws_kl[bid] = redA[0] + redA[1] + redA[2] + redA[3];
}

// ---------------------------------------------------------------------------
// Kernel 3: deterministic single-block loss reduction.
// ---------------------------------------------------------------------------
__global__ __launch_bounds__(256)
void loss_reduce(const float* __restrict__ ws_kl,
                 const int* __restrict__ seg32,
                 float* __restrict__ out_loss, int rows)
{
    const int tid = threadIdx.x;
    float s = 0.f, c = 0.f;
    for (int i = tid; i < rows; i += 256) {
        s += ws_kl[i];
        c += (seg32[i] != 0) ? 1.f : 0.f;
    }
#pragma unroll
    for (int off = 32; off >= 1; off >>= 1) {
        s += __shfl_xor(s, off, 64);
        c += __shfl_xor(c, off, 64);
    }
    __shared__ float sA[4], sB[4];
    const int lane = tid & 63, wv = tid >> 6;
    if (lane == 0) { sA[wv] = s; sB[wv] = c; }
    __syncthreads();
    if (tid == 0) {
        float ts = sA[0] + sA[1] + sA[2] + sA[3];
        float tc = sB[0] + sB[1] + sB[2] + sB[3];
        out_loss[0] = ts / (tc + 1e-9f);
    }
}

// ---------------------------------------------------------------------------
extern "C" void kernel_launch(void* const* d_in, const int* in_sizes, int n_in,
                              void* d_out, int out_size, void* d_ws, size_t ws_size,
                              hipStream_t stream)
{
    const float* key_f   = (const float*)d_in[0];
    const float* query_f = (const float*)d_in[1];
    const int*   seg32   = (const int*)d_in[2];
    const int*   inds    = (const int*)d_in[3];
    float* out = (float*)d_out;

    const int N    = NPIX;
    const int rows = in_sizes[2];            // B*N
    const int S    = in_sizes[3] / rows;     // 1024
    const float scale = (float)(1.0 / sqrt((double)CDIM));

    // ws layout: key16 rows | q16 rows | seg8 | kl array
    const size_t off_q16 = (size_t)rows * 64;
    const size_t off_s8  = off_q16 + (size_t)rows * 64;
    const size_t off_kl  = (off_s8 + (size_t)rows + 255) & ~(size_t)255;
    const size_t need    = off_kl + (size_t)rows * 4;

    uint8_t* wsb = (uint8_t*)d_ws;
    const bool geom_ok = (S == SSAM) && (rows % N == 0);

    if (ws_size >= need && geom_ok) {
        uint8_t* key16 = wsb;
        uint8_t* q16   = wsb + off_q16;
        uint8_t* seg8  = wsb + off_s8;
        float*   wskl  = (float*)(wsb + off_kl);

        prep_kernel<<<(rows + 255) / 256, 256, 0, stream>>>(
            key_f, query_f, seg32, key16, q16, seg8, N, rows, scale);
        affinity_coop<<<rows, 256, 0, stream>>>(
            inds, key16, q16, seg8, out, wskl);
        loss_reduce<<<1, 256, 0, stream>>>(wskl, seg32, out + (size_t)rows * S, rows);
    } else {
        float* wskl = (float*)d_ws;
        affinity_fallback<<<rows, 256, 0, stream>>>(
            key_f, query_f, seg32, inds, out, wskl, N, S, scale);
        loss_reduce<<<1, 256, 0, stream>>>(wskl, seg32, out + (size_t)rows * S, rows);
    }
}

// Round 7
// 168.721 us; speedup vs baseline: 2.6985x; 1.1274x over previous
//
#include <hip/hip_runtime.h>
#include <stdint.h>

typedef _Float16 h2 __attribute__((ext_vector_type(2)));

static constexpr int CDIM = 32;     // channels
static constexpr int NPIX = 16384;  // H*W
static constexpr int SSAM = 1024;   // samples per row
static constexpr int ROWS_PER_BLOCK = 16;

__device__ __forceinline__ uint16_t f2h(float f) {
    union { _Float16 h; uint16_t u; } c;
    c.h = (_Float16)f;
    return c.u;
}

// cross-lane add via DPP quad_perm (VALU-only, no LDS pipe).
template<int CTRL>
__device__ __forceinline__ float dpp_add(float x) {
    int y = __builtin_amdgcn_mov_dpp(__float_as_int(x), CTRL, 0xF, 0xF, true);
    return x + __int_as_float(y);
}

__device__ __forceinline__ float dot2(h2 a, h2 b, float c) {
    return __builtin_amdgcn_fdot2(a, b, c, false);   // v_dot2_f32_f16
}

// ---------------------------------------------------------------------------
// Kernel 1: layout prep.
//   key_feat  [B][C][N] f32 -> key16 [B*N][32] f16 rows (64B, line-aligned)
//   query_feat[B][C][N] f32 -> q16   [B*N][32] f16 rows, PRE-SCALED by C^-0.5
//   seg32     [B*N] i32     -> seg8  [B*N] u8
// ---------------------------------------------------------------------------
__global__ __launch_bounds__(256)
void prep_kernel(const float* __restrict__ key_f,
                 const float* __restrict__ query_f,
                 const int* __restrict__ seg32,
                 uint8_t* __restrict__ key16,
                 uint8_t* __restrict__ q16,
                 uint8_t* __restrict__ seg8,
                 int N, int rows, float scale)
{
    int gI = blockIdx.x * 256 + threadIdx.x;
    if (gI >= rows) return;
    int b = gI / N, n = gI - b * N;
    const size_t cb = (size_t)b * CDIM;

    uint32_t kp[16], qp[16];
#pragma unroll
    for (int c = 0; c < CDIM; c += 2) {
        float k0 = key_f[(cb + c) * N + n];
        float k1 = key_f[(cb + c + 1) * N + n];
        float q0 = query_f[(cb + c) * N + n] * scale;
        float q1 = query_f[(cb + c + 1) * N + n] * scale;
        kp[c >> 1] = (uint32_t)f2h(k0) | ((uint32_t)f2h(k1) << 16);
        qp[c >> 1] = (uint32_t)f2h(q0) | ((uint32_t)f2h(q1) << 16);
    }
    uint4* ko = (uint4*)(key16 + ((size_t)gI << 6));
    uint4* qo = (uint4*)(q16 + ((size_t)gI << 6));
#pragma unroll
    for (int j = 0; j < 4; ++j) {
        ko[j] = make_uint4(kp[4*j], kp[4*j+1], kp[4*j+2], kp[4*j+3]);
        qo[j] = make_uint4(qp[4*j], qp[4*j+1], qp[4*j+2], qp[4*j+3]);
    }
    seg8[gI] = (uint8_t)seg32[gI];
}

// ---------------------------------------------------------------------------
// Kernel 2 (fast): persistent 16-row blocks, cooperative gather, fused KL.
// Per block: stage batch seg (16KB) ONCE; per row: 16-deep pinned gather
// pipeline (sched_barrier), idx double-buffer with prefetch-under-compute.
// 4 lanes per sample; v_dot2_f32_f16; DPP group reduce.
// Fixed geometry: N=16384, S=1024, C=32, 16 rows/block.
// ---------------------------------------------------------------------------
__global__ __launch_bounds__(256)
void affinity_multi(const int* __restrict__ inds,
                    const uint8_t* __restrict__ key16,
                    const uint8_t* __restrict__ q16,
                    const uint8_t* __restrict__ seg8,
                    float* __restrict__ out,
                    float* __restrict__ ws_kl)
{
    const int tid  = threadIdx.x;
    const int row0 = blockIdx.x * ROWS_PER_BLOCK;
    const int b    = row0 >> 14;           // N = 16384; 16 | N so batch uniform
    const int lane = tid & 63;
    const int w    = tid >> 6;             // wave 0..3
    const int g    = lane >> 2;            // group 0..15
    const int sub  = lane & 3;             // quarter 0..3

    __shared__ __align__(16) uint8_t seg_lds[NPIX];     // 16KB, staged once
    __shared__ __align__(16) int     idx_lds[2][SSAM];  // 2 x 4KB double buffer
    __shared__ float redA[4], redB[4], redC[4];

    // ---- block prologue: stage seg (once) + idx row0 + q row0 ----
    const uint8_t* sbg = seg8 + ((size_t)b << 14);
#pragma unroll
    for (int r = 0; r < 4; ++r)
        ((uint4*)seg_lds)[(r << 8) + tid] = ((const uint4*)sbg)[(r << 8) + tid];
    ((int4*)idx_lds[0])[tid] = ((const int4*)(inds + ((size_t)row0 << 10)))[tid];
    uint4 qcur = *(const uint4*)(q16 + ((size_t)row0 << 6) + (sub << 4));
    __syncthreads();

    const uint8_t* kb = key16 + ((size_t)b << 20);      // b * N * 64
    const uint32_t subs = (uint32_t)(sub << 4);
    const int sbase = (w << 8) + g;                     // sample = sbase + i*16

    for (int r = 0; r < ROWS_PER_BLOCK; ++r) {
        const int row = row0 + r;
        const int* cur = idx_lds[r & 1];
        const bool hasNext = (r + 1 < ROWS_PER_BLOCK);

        // unpack this row's query fragment (loaded last iteration)
        h2 qh0, qh1, qh2, qh3;
        {
            union { uint4 u; h2 h[4]; } qc; qc.u = qcur;
            qh0 = qc.h[0]; qh1 = qc.h[1]; qh2 = qc.h[2]; qh3 = qc.h[3];
        }
        const int seg_n = (int)seg_lds[row & 0x3FFF];

        // ---- phase 1: 16 indices from LDS ----
        int idxs[16];
#pragma unroll
        for (int i = 0; i < 16; ++i)
            idxs[i] = cur[sbase + (i << 4)];

        // ---- phase 2: issue all 16 key gathers (pinned above consumption) --
        uint4 kd[16];
#pragma unroll
        for (int i = 0; i < 16; ++i)
            kd[i] = *(const uint4*)(kb + (((uint32_t)idxs[i] << 6) | subs));
        __builtin_amdgcn_sched_barrier(0);

        // ---- prefetch next row (younger than gathers in the vmcnt FIFO) ----
        int4 pre; uint4 qnext;
        if (hasNext) {
            pre   = ((const int4*)(inds + ((size_t)(row + 1) << 10)))[tid];
            qnext = *(const uint4*)(q16 + ((size_t)(row + 1) << 6) + (sub << 4));
        }
        __builtin_amdgcn_sched_barrier(0);

        // ---- target flags on the LDS pipe while gathers are in flight ----
        int tfm = 0;
#pragma unroll
        for (int j = 0; j < 4; ++j) {
            int idx = cur[sbase + (((j << 2) | sub) << 4)];
            if ((int)seg_lds[idx] == seg_n) tfm |= 1 << j;
        }

        // ---- phase 3: dots, group reduce ----
        float lgo0 = 0.f, lgo1 = 0.f, lgo2 = 0.f, lgo3 = 0.f;
        float m = -1e30f;
#pragma unroll
        for (int i = 0; i < 16; ++i) {
            union { uint4 u; h2 h[4]; } kc; kc.u = kd[i];
            float acc = dot2(kc.h[0], qh0, 0.f);
            acc = dot2(kc.h[1], qh1, acc);
            acc = dot2(kc.h[2], qh2, acc);
            acc = dot2(kc.h[3], qh3, acc);
            acc = dpp_add<0xB1>(acc);      // xor 1
            acc = dpp_add<0x4E>(acc);      // xor 2 -> all 4 lanes hold dot
            m = fmaxf(m, acc);
            if (sub == (i & 3)) {          // owner capture (cndmask)
                if ((i >> 2) == 0) lgo0 = acc;
                if ((i >> 2) == 1) lgo1 = acc;
                if ((i >> 2) == 2) lgo2 = acc;
                if ((i >> 2) == 3) lgo3 = acc;
            }
        }

        // ---- owner-lane full-wave logit stores (4 insts, full segments) ----
        const size_t rowbase = (size_t)row << 10;
        float* op = out + rowbase + (w << 8) + (sub << 4) + g;
        op[0]   = lgo0;
        op[64]  = lgo1;
        op[128] = lgo2;
        op[192] = lgo3;

        // ---- row max (quad-uniform -> 4-step butterfly) ----
#pragma unroll
        for (int off = 32; off >= 4; off >>= 1)
            m = fmaxf(m, __shfl_xor(m, off, 64));
        if (lane == 0) redA[w] = m;
        __syncthreads();                                   // sync 1
        m = fmaxf(fmaxf(redA[0], redA[1]), fmaxf(redA[2], redA[3]));

        // ---- Z = sum exp (each sample once), T = target count ----
        float e0 = __expf(lgo0 - m), e1 = __expf(lgo1 - m);
        float e2 = __expf(lgo2 - m), e3 = __expf(lgo3 - m);
        float z = (e0 + e1) + (e2 + e3);
        float tcnt = (float)__popc((unsigned)tfm);
#pragma unroll
        for (int off = 32; off >= 1; off >>= 1) {
            z    += __shfl_xor(z, off, 64);
            tcnt += __shfl_xor(tcnt, off, 64);
        }
        if (lane == 0) { redB[w] = z; redC[w] = tcnt; }
        __syncthreads();                                   // sync 2
        const float Z = redB[0] + redB[1] + redB[2] + redB[3];
        const float T = redC[0] + redC[1] + redC[2] + redC[3];

        // ---- KL contribution ----
        float kl = 0.f;
        if (seg_n != 0) {
            const float invZ = 1.f / (Z + 1e-9f);
            const float invT = 1.f / (T + 1e-9f);
            const float nlT  = -__logf(T + 1e-9f);
            if (tfm & 1) kl += invT * (nlT - __logf(fmaxf(e0 * invZ, 1e-8f)));
            if (tfm & 2) kl += invT * (nlT - __logf(fmaxf(e1 * invZ, 1e-8f)));
            if (tfm & 4) kl += invT * (nlT - __logf(fmaxf(e2 * invZ, 1e-8f)));
            if (tfm & 8) kl += invT * (nlT - __logf(fmaxf(e3 * invZ, 1e-8f)));
        }
#pragma unroll
        for (int off = 32; off >= 1; off >>= 1)
            kl += __shfl_xor(kl, off, 64);
        if (lane == 0) redA[w] = kl;
        __syncthreads();                                   // sync 3
        if (tid == 0)
            ws_kl[row] = redA[0] + redA[1] + redA[2] + redA[3];

        // ---- commit prefetch into the other buffer ----
        if (hasNext) {
            ((int4*)idx_lds[(r + 1) & 1])[tid] = pre;
            qcur = qnext;
        }
        __syncthreads();                                   // sync 4 (visibility)
    }
}

// ---------------------------------------------------------------------------
// Fallback (generic shapes / tiny ws): per-thread gather from native layout.
// ---------------------------------------------------------------------------
__global__ __launch_bounds__(256)
void affinity_fallback(const float* __restrict__ key_f,
                       const float* __restrict__ query_f,
                       const int*   __restrict__ seg32,
                       const int*   __restrict__ inds,
                       float* __restrict__ out,
                       float* __restrict__ ws_kl,
                       int N, int S, float scale)
{
    const int bid = blockIdx.x;
    const int tid = threadIdx.x;
    const int b   = bid / N;

    __shared__ float q_lds[CDIM];
    __shared__ float redA[4], redB[4], redC[4];

    if (tid < CDIM) {
        int n = bid - b * N;
        q_lds[tid] = query_f[((size_t)(b * CDIM + tid)) * N + n];
    }
    const int seg_n = seg32[bid];
    __syncthreads();

    float q[CDIM];
#pragma unroll
    for (int c = 0; c < CDIM; ++c) q[c] = q_lds[c];

    const size_t rowbase = (size_t)bid * S;
    const int4 iv = ((const int4*)(inds + rowbase))[tid];
    const int idxv[4] = {iv.x, iv.y, iv.z, iv.w};

    float lg[4];
    int   tf[4];
#pragma unroll
    for (int k = 0; k < 4; ++k) {
        int idx = idxv[k];
        tf[k] = (seg32[b * N + idx] == seg_n) ? 1 : 0;
        float acc = 0.f;
#pragma unroll
        for (int c = 0; c < CDIM; ++c)
            acc = fmaf(key_f[((size_t)(b * CDIM + c)) * N + idx], q[c], acc);
        lg[k] = acc * scale;
    }
    ((float4*)(out + rowbase))[tid] = make_float4(lg[0], lg[1], lg[2], lg[3]);

    const int lane = tid & 63, wv = tid >> 6;
    float m = fmaxf(fmaxf(lg[0], lg[1]), fmaxf(lg[2], lg[3]));
#pragma unroll
    for (int off = 32; off >= 1; off >>= 1)
        m = fmaxf(m, __shfl_xor(m, off, 64));
    if (lane == 0) redA[wv] = m;
    __syncthreads();
    m = fmaxf(fmaxf(redA[0], redA[1]), fmaxf(redA[2], redA[3]));

    float e[4], z = 0.f, tcnt = 0.f;
#pragma unroll
    for (int k = 0; k < 4; ++k) {
        e[k] = expf(lg[k] - m);
        z += e[k];
        tcnt += (float)tf[k];
    }
#pragma unroll
    for (int off = 32; off >= 1; off >>= 1) {
        z    += __shfl_xor(z, off, 64);
        tcnt += __shfl_xor(tcnt, off, 64);
    }
    if (lane == 0) { redB[wv] = z; redC[wv] = tcnt; }
    __syncthreads();
    const float Z = redB[0] + redB[1] + redB[2] + redB[3];
    const float T = redC[0] + redC[1] + redC[2] + redC[3];

    float kl = 0.f;
    if (seg_n != 0) {
        const float invZ = 1.f / (Z + 1e-9f);
        const float invT = 1.f / (T + 1e-9f);
        const float nlT  = -logf(T + 1e-9f);
#pragma unroll
        for (int k = 0; k < 4; ++k) {
            if (tf[k]) {
                float p = e[k] * invZ;
                float yp = logf(fmaxf(p, 1e-8f));
                kl += invT * (nlT - yp);
            }
        }
    }
#pragma unroll
    for (int off = 32; off >= 1; off >>= 1)
        kl += __shfl_xor(kl, off, 64);
    if (lane == 0) redA[wv] = kl;
    __syncthreads();
    if (tid == 0)
        ws_kl[bid] = redA[0] + redA[1] + redA[2] + redA[3];
}

// ---------------------------------------------------------------------------
// Kernel 3: deterministic single-block loss reduction (1024 threads).
// ---------------------------------------------------------------------------
__global__ __launch_bounds__(1024)
void loss_reduce(const float* __restrict__ ws_kl,
                 const int* __restrict__ seg32,
                 float* __restrict__ out_loss, int rows)
{
    const int tid = threadIdx.x;
    float s = 0.f, c = 0.f;
    for (int i = tid; i < rows; i += 1024) {
        s += ws_kl[i];
        c += (seg32[i] != 0) ? 1.f : 0.f;
    }
#pragma unroll
    for (int off = 32; off >= 1; off >>= 1) {
        s += __shfl_xor(s, off, 64);
        c += __shfl_xor(c, off, 64);
    }
    __shared__ float sA[16], sB[16];
    const int lane = tid & 63, wv = tid >> 6;
    if (lane == 0) { sA[wv] = s; sB[wv] = c; }
    __syncthreads();
    if (tid == 0) {
        float ts = 0.f, tc = 0.f;
#pragma unroll
        for (int k = 0; k < 16; ++k) { ts += sA[k]; tc += sB[k]; }
        out_loss[0] = ts / (tc + 1e-9f);
    }
}

// ---------------------------------------------------------------------------
extern "C" void kernel_launch(void* const* d_in, const int* in_sizes, int n_in,
                              void* d_out, int out_size, void* d_ws, size_t ws_size,
                              hipStream_t stream)
{
    const float* key_f   = (const float*)d_in[0];
    const float* query_f = (const float*)d_in[1];
    const int*   seg32   = (const int*)d_in[2];
    const int*   inds    = (const int*)d_in[3];
    float* out = (float*)d_out;

    const int N    = NPIX;
    const int rows = in_sizes[2];            // B*N
    const int S    = in_sizes[3] / rows;     // 1024
    const float scale = (float)(1.0 / sqrt((double)CDIM));

    // ws layout: key16 rows | q16 rows | seg8 | kl array
    const size_t off_q16 = (size_t)rows * 64;
    const size_t off_s8  = off_q16 + (size_t)rows * 64;
    const size_t off_kl  = (off_s8 + (size_t)rows + 255) & ~(size_t)255;
    const size_t need    = off_kl + (size_t)rows * 4;

    uint8_t* wsb = (uint8_t*)d_ws;
    const bool geom_ok = (S == SSAM) && (rows % N == 0) &&
                         (rows % ROWS_PER_BLOCK == 0);

    if (ws_size >= need && geom_ok) {
        uint8_t* key16 = wsb;
        uint8_t* q16   = wsb + off_q16;
        uint8_t* seg8  = wsb + off_s8;
        float*   wskl  = (float*)(wsb + off_kl);

        prep_kernel<<<(rows + 255) / 256, 256, 0, stream>>>(
            key_f, query_f, seg32, key16, q16, seg8, N, rows, scale);
        affinity_multi<<<rows / ROWS_PER_BLOCK, 256, 0, stream>>>(
            inds, key16, q16, seg8, out, wskl);
        loss_reduce<<<1, 1024, 0, stream>>>(wskl, seg32, out + (size_t)rows * S, rows);
    } else {
        float* wskl = (float*)d_ws;
        affinity_fallback<<<rows, 256, 0, stream>>>(
            key_f, query_f, seg32, inds, out, wskl, N, S, scale);
        loss_reduce<<<1, 1024, 0, stream>>>(wskl, seg32, out + (size_t)rows * S, rows);
    }
}